// Round 7
// baseline (632.641 us; speedup 1.0000x reference)
//
#include <hip/hip_runtime.h>

typedef unsigned short u16;
typedef unsigned int   u32;
typedef __attribute__((ext_vector_type(8)))  short short8;   // 8 bf16 (4 VGPRs)
typedef __attribute__((ext_vector_type(16))) float floatx16; // 32x32 MFMA C/D
typedef __attribute__((ext_vector_type(8)))  u16   u16x8;
typedef __attribute__((ext_vector_type(4)))  u16   u16x4;

__device__ __forceinline__ u16 f2b(float f) {
    u32 u = __float_as_uint(f);
    u = (u + 0x7FFFu + ((u >> 16) & 1u)) >> 16;
    return (u16)u;
}
__device__ __forceinline__ float b2f(u16 h) {
    return __uint_as_float(((u32)h) << 16);
}

// ================= prep building blocks (256-thread granularity) ===========
__device__ __forceinline__ void f2b_block(const float* __restrict__ src,
                                          u16* __restrict__ dst, int blk) {
    int i = blk * 256 + threadIdx.x;
    float4 v = ((const float4*)src)[i];
    u16x4 o;
    o[0] = f2b(v.x); o[1] = f2b(v.y); o[2] = f2b(v.z); o[3] = f2b(v.w);
    *(u16x4*)&dst[i * 4] = o;
}

__device__ __forceinline__ void pad_block(const float* __restrict__ Wsrc, int rows,
                                          u16* __restrict__ Wdst,
                                          const float* __restrict__ bsrc,
                                          float* __restrict__ bdst, int blk) {
    int i = blk * 256 + threadIdx.x;        // 32768 total (128x1024/4)
    int idx = i * 4;
    int r = idx >> 10;
    int c = idx & 1023;
    u16x4 o;
    if (r < rows) {
        float4 v = *(const float4*)&Wsrc[r * 1024 + c];
        o[0] = f2b(v.x); o[1] = f2b(v.y); o[2] = f2b(v.z); o[3] = f2b(v.w);
    } else {
        o[0] = 0; o[1] = 0; o[2] = 0; o[3] = 0;
    }
    *(u16x4*)&Wdst[idx] = o;
    if (i < 128) bdst[i] = (i < rows) ? bsrc[i] : 0.f;
}

__device__ __forceinline__ void l1_block(const float* __restrict__ x,
                                         const float* __restrict__ W1,
                                         const float* __restrict__ b1,
                                         u16* __restrict__ h1, int blk) {
    const int t  = threadIdx.x;
    const int b0 = blk * 16;
    const int n0 = t * 8;
    float4 wreg[8]; float breg[8];
    const float4* W14 = (const float4*)W1;
#pragma unroll
    for (int i = 0; i < 8; ++i) { wreg[i] = W14[n0 + i]; breg[i] = b1[n0 + i]; }
    for (int r = 0; r < 16; ++r) {
        int b = b0 + r;
        float4 xv = ((const float4*)x)[b];
        u16x8 o;
#pragma unroll
        for (int i = 0; i < 8; ++i) {
            float s = xv.x * wreg[i].x + xv.y * wreg[i].y +
                      xv.z * wreg[i].z + xv.w * wreg[i].w + breg[i];
            s = fmaxf(s, 0.f);
            o[i] = f2b(s);
        }
        *(u16x8*)&h1[(size_t)b * 2048 + n0] = o;
    }
}

// ===== stage-1 prep: only what gates the L2 GEMM (W2 convert + layer 1) ====
__global__ __launch_bounds__(256)
void k_prep1(const float* W2, u16* W2b,
             const float* x, const float* W1, const float* b1, u16* h1) {
    int blk = blockIdx.x;
    if (blk < 4096) { f2b_block(W2, W2b, blk); return; }
    l1_block(x, W1, b1, h1, blk - 4096);
}

// ===== backfill prep (extra blocks inside the L2 GEMM dispatch) ============
__device__ __forceinline__ void backfill_prep(
        int pblk,
        const float* W31, u16* W31b, const float* W32, u16* W32b,
        const float* W41, u16* W41b, const float* W42, u16* W42b,
        const float* W51, u16* W51p, const float* b51, float* b51p,
        const float* W52, u16* W52p, const float* b52, float* b52p,
        const float* b31, const float* b32, float* b3c) {
    if (pblk < 2048) { f2b_block(W31, W31b, pblk); return; }   pblk -= 2048;
    if (pblk < 2048) { f2b_block(W32, W32b, pblk); return; }   pblk -= 2048;
    if (pblk < 1024) { f2b_block(W41, W41b, pblk); return; }   pblk -= 1024;
    if (pblk < 1024) { f2b_block(W42, W42b, pblk); return; }   pblk -= 1024;
    if (pblk < 128)  { pad_block(W51, 20, W51p, b51, b51p, pblk); return; } pblk -= 128;
    if (pblk < 128)  { pad_block(W52, 11, W52p, b52, b52p, pblk); return; } pblk -= 128;
    if (pblk < 8) {
        int i = pblk * 256 + threadIdx.x;
        b3c[i] = (i < 1024) ? b31[i] : b32[i - 1024];
    }
}

// ================= pipelined bf16 MFMA GEMM: 128x128, BK=64, NO s_barrier ==
// C[M,N] = act(A[M,K] @ W[N,K]^T + b). 256 threads = 4 waves, each 64x64
// via 2x2 mfma_f32_32x32x16_bf16. Double-buffered LDS stages with LDS-flag
// rendezvous instead of __syncthreads in the K-loop: each wave issues its 8
// global_load_lds for stage j+1 a full stage early, waits only for ITS OWN
// stage-j loads via s_waitcnt vmcnt(8) (per-wave counter), then counts into
// ready[j]; buffer reuse is gated by done[j]. No collective vmcnt(0) drain
// anywhere in the loop -> load latency hidden behind compute.
// LDS 65 KB -> 2 blocks/CU. XOR chunk swizzle as before. XCD-aware swizzle.
// Optional second GEMM (A2/W2g/bias2/C2) for swizzled by >= split; blocks
// beyond gemmY rows run backfill weight-prep.
__global__ __launch_bounds__(256, 2)
void k_gemm_pl(const u16* __restrict__ A, const u16* __restrict__ W,
               const float* __restrict__ bias, u16* __restrict__ C,
               int K, int lda, int ldc, int relu, int gemmY,
               const u16* A2, const u16* W2g, const float* bias2, u16* C2,
               int split,
               const float* W31, u16* W31b, const float* W32, u16* W32b,
               const float* W41, u16* W41b, const float* W42, u16* W42b,
               const float* W51, u16* W51p, const float* b51, float* b51p,
               const float* W52, u16* W52p, const float* b52, float* b52p,
               const float* b31, const float* b32, float* b3c) {
    const int ngemm = gemmY * gridDim.x;
    int flat = blockIdx.y * gridDim.x + blockIdx.x;
    if (flat >= ngemm) {
        backfill_prep(flat - ngemm, W31, W31b, W32, W32b, W41, W41b,
                      W42, W42b, W51, W51p, b51, b51p, W52, W52p, b52, b52p,
                      b31, b32, b3c);
        return;
    }

    __shared__ __align__(16) u16 As[2 * 128 * 64];  // 32 KB (2 stages)
    __shared__ __align__(16) u16 Ws[2 * 128 * 64];  // 32 KB
    __shared__ int ready[32];
    __shared__ int done[32];

    const int tid  = threadIdx.x;
    const int wave = tid >> 6;
    const int lane = tid & 63;

    if (tid < 32) { ready[tid] = 0; done[tid] = 0; }
    __syncthreads();   // once, before the loop

    // XCD swizzle (valid permutation when gemmY % 8 == 0)
    int xcd = flat & 7;
    int p   = flat >> 3;
    int bx  = p % gridDim.x;
    int by  = (p / gridDim.x) * 8 + xcd;

    if (A2 != nullptr && by >= split) {
        A = A2; W = W2g; bias = bias2; C = C2; by -= split;
    }
    const int bm = by * 128;
    const int bn = bx * 128;

    // staging: 8 loads/wave/stage. lane -> row lane>>3 of its chunk-group,
    // physical chunk lane&7 holding logical chunk (lane&7)^(lane>>3).
    const int srow = lane >> 3;
    const int sg   = ((lane & 7) ^ srow) * 8;

    const int wm    = (wave & 1) * 64;
    const int wn    = (wave >> 1) * 64;
    const int row32 = lane & 31;
    const int half  = lane >> 5;

    floatx16 acc[2][2];
#pragma unroll
    for (int i = 0; i < 2; ++i)
#pragma unroll
        for (int j = 0; j < 2; ++j)
#pragma unroll
            for (int r = 0; r < 16; ++r) acc[i][j][r] = 0.f;

    const int niter = K >> 6;

    auto issue = [&](int j) {
        const int k0 = j << 6;
        const int so = (j & 1) << 13;      // stage offset in u16
#pragma unroll
        for (int i = 0; i < 4; ++i) {
            int ci = wave * 4 + i;
            int r  = ci * 8 + srow;
            const u16* ga = A + (size_t)(bm + r) * lda + k0 + sg;
            __builtin_amdgcn_global_load_lds(
                (const __attribute__((address_space(1))) void*)ga,
                (__attribute__((address_space(3))) void*)&As[so + ci * 512], 16, 0, 0);
            const u16* gw = W + (size_t)(bn + r) * K + k0 + sg;
            __builtin_amdgcn_global_load_lds(
                (const __attribute__((address_space(1))) void*)gw,
                (__attribute__((address_space(3))) void*)&Ws[so + ci * 512], 16, 0, 0);
        }
    };

    auto compute = [&](int j) {
        const int so = (j & 1) << 13;
#pragma unroll
        for (int s = 0; s < 4; ++s) {
            const int c = s * 2 + half;
            short8 a0, a1, b0, b1;
            { int r = wm + row32;       a0 = *(const short8*)&As[so + r * 64 + ((c ^ (r & 7)) * 8)]; }
            { int r = wm + 32 + row32;  a1 = *(const short8*)&As[so + r * 64 + ((c ^ (r & 7)) * 8)]; }
            { int r = wn + row32;       b0 = *(const short8*)&Ws[so + r * 64 + ((c ^ (r & 7)) * 8)]; }
            { int r = wn + 32 + row32;  b1 = *(const short8*)&Ws[so + r * 64 + ((c ^ (r & 7)) * 8)]; }
            acc[0][0] = __builtin_amdgcn_mfma_f32_32x32x16_bf16(a0, b0, acc[0][0], 0, 0, 0);
            acc[0][1] = __builtin_amdgcn_mfma_f32_32x32x16_bf16(a0, b1, acc[0][1], 0, 0, 0);
            acc[1][0] = __builtin_amdgcn_mfma_f32_32x32x16_bf16(a1, b0, acc[1][0], 0, 0, 0);
            acc[1][1] = __builtin_amdgcn_mfma_f32_32x32x16_bf16(a1, b1, acc[1][1], 0, 0, 0);
        }
    };

    // prologue: stages 0 and 1 in flight
    issue(0);
    if (niter > 1) issue(1);
    asm volatile("" ::: "memory");

    for (int j = 0; j < niter; ++j) {
        // wait for OWN stage-j loads only (8 newer loads may stay in flight)
        if (j + 1 < niter) asm volatile("s_waitcnt vmcnt(8)" ::: "memory");
        else               asm volatile("s_waitcnt vmcnt(0)" ::: "memory");
        if (lane == 0) atomicAdd(&ready[j], 1);
        {
            volatile int* rp = (volatile int*)&ready[j];
            while (*rp < 4) { }
        }
        asm volatile("" ::: "memory");   // no ds_read speculation above the spin
        compute(j);
        asm volatile("" ::: "memory");   // ds_reads of stage j retired below here
        if (j + 2 < niter) {
            if (lane == 0) atomicAdd(&done[j], 1);
            volatile int* dp = (volatile int*)&done[j];
            while (*dp < 4) { }
            asm volatile("" ::: "memory");
            issue(j + 2);                // overwrite buffer (j&1), all waves done
            asm volatile("" ::: "memory");
        }
    }

    // epilogue: C/D layout col=lane&31, row=(reg&3)+8*(reg>>2)+4*(lane>>5)
    float bv[2];
#pragma unroll
    for (int j = 0; j < 2; ++j) bv[j] = bias[bn + wn + j * 32 + row32];
#pragma unroll
    for (int i = 0; i < 2; ++i)
#pragma unroll
        for (int j = 0; j < 2; ++j)
#pragma unroll
            for (int r = 0; r < 16; ++r) {
                int row = bm + wm + i * 32 + (r & 3) + 8 * (r >> 2) + 4 * half;
                int col = bn + wn + j * 32 + row32;
                float v = acc[i][j][r] + bv[j];
                if (relu) v = fmaxf(v, 0.f);
                C[(size_t)row * ldc + col] = f2b(v);
            }
}

// ================= final: heads + physics + QP + softmax combine ===========
__global__ __launch_bounds__(256)
void k_final(const u16* __restrict__ x51b, const u16* __restrict__ x52b,
             const float* __restrict__ x, const float* __restrict__ mean,
             const float* __restrict__ std_, const float* __restrict__ mean_label,
             const float* __restrict__ std_label, const float* __restrict__ wt,
             float* __restrict__ out) {
    int b = blockIdx.x * blockDim.x + threadIdx.x;   // < 16384

    float w[10], m = -1e30f;
#pragma unroll
    for (int h = 0; h < 10; ++h) { w[h] = wt[h]; m = fmaxf(m, w[h]); }
    float s = 0.f;
#pragma unroll
    for (int h = 0; h < 10; ++h) { w[h] = __expf(w[h] - m); s += w[h]; }
    float winv = 1.f / s;

    float4 xv = ((const float4*)x)[b];
    float th1 = xv.x * std_[0] + mean[0];
    float w1v = xv.y * std_[1] + mean[1];
    float th2 = xv.z * std_[2] + mean[2];
    float w2v = xv.w * std_[3] + mean[3];
    float s1 = sinf(th1), c1 = cosf(th1);
    float s2 = sinf(th2), c2 = cosf(th2);
    float px = 3.f * c1 + 3.f * c2 - 0.f;
    float py = 3.f * s1 + 3.f * s2 - 7.f;
    float vx = -3.f * s1 * w1v - 3.f * s2 * w2v;
    float vy =  3.f * c1 * w1v + 3.f * c2 * w2v;
    float barrier = px * px + py * py - 16.f;
    float b_dot = 2.f * (px * vx + py * vy);
    float Lf2b = 2.f * vx * vx + 2.f * vy * vy
               + 2.f * px * (-3.f * c1 * w1v * w1v - 3.f * c2 * w2v * w2v)
               + 2.f * py * (-3.f * s1 * w1v * w1v - 3.f * s2 * w2v * w2v);
    float g1 = 2.f * px * (-3.f * s1) + 2.f * py * (3.f * c1);
    float g2 = 2.f * px * (-3.f * s2) + 2.f * py * (3.f * c2);
    float Gx = -g1, Gy = -g2;
    float Gdot = Gx * Gx + Gy * Gy;

    float alpha = 4.f / (1.f + expf(-b2f(x52b[(size_t)b * 128 + 0])));

    float rx = 0.f, ry = 0.f;
#pragma unroll
    for (int h = 0; h < 10; ++h) {
        float r0 = b2f(x51b[(size_t)b * 128 + 2 * h]);
        float r1 = b2f(x51b[(size_t)b * 128 + 2 * h + 1]);
        float beta = 4.f / (1.f + expf(-b2f(x52b[(size_t)b * 128 + 1 + h])));
        float hh = Lf2b + (alpha + beta) * b_dot + alpha * beta * barrier;
        float ux = -r0, uy = -r1;
        float viol = ux * Gx + uy * Gy - hh;
        float lam = fmaxf(viol / Gdot, 0.f);
        float sx = ux - lam * Gx;
        float sy = uy - lam * Gy;
        float wk = w[h] * winv;
        rx += wk * sx; ry += wk * sy;
    }
    out[2 * b]     = (rx - mean_label[0]) / std_label[0];
    out[2 * b + 1] = (ry - mean_label[1]) / std_label[1];
}

extern "C" void kernel_launch(void* const* d_in, const int* in_sizes, int n_in,
                              void* d_out, int out_size, void* d_ws, size_t ws_size,
                              hipStream_t stream) {
    const float* x    = (const float*)d_in[0];
    const float* mean = (const float*)d_in[2];
    const float* std_ = (const float*)d_in[3];
    const float* mean_label = (const float*)d_in[4];
    const float* std_label  = (const float*)d_in[5];
    const float* W1  = (const float*)d_in[6];
    const float* b1  = (const float*)d_in[7];
    const float* W2  = (const float*)d_in[8];
    const float* b2  = (const float*)d_in[9];
    const float* W31 = (const float*)d_in[10];
    const float* b31 = (const float*)d_in[11];
    const float* W32 = (const float*)d_in[12];
    const float* b32 = (const float*)d_in[13];
    const float* W41 = (const float*)d_in[14];
    const float* b41 = (const float*)d_in[15];
    const float* W42 = (const float*)d_in[16];
    const float* b42 = (const float*)d_in[17];
    const float* W51 = (const float*)d_in[18];
    const float* b51 = (const float*)d_in[19];
    const float* W52 = (const float*)d_in[20];
    const float* b52 = (const float*)d_in[21];
    const float* wt  = (const float*)d_in[22];

    const int B = in_sizes[0] / 4;       // 16384

    char* wsp = (char*)d_ws;
    size_t off = 0;
    auto alloc = [&](size_t bytes) {
        void* p = wsp + off;
        off += (bytes + 255) & ~(size_t)255;
        return p;
    };
    u16*   W2b  = (u16*)  alloc((size_t)2048 * 2048 * 2);
    u16*   W31b = (u16*)  alloc((size_t)1024 * 2048 * 2);  // W31b||W32b contiguous
    u16*   W32b = (u16*)  alloc((size_t)1024 * 2048 * 2);  //   = [2048][2048] weight
    u16*   W41b = (u16*)  alloc((size_t)1024 * 1024 * 2);
    u16*   W42b = (u16*)  alloc((size_t)1024 * 1024 * 2);
    u16*   W51p = (u16*)  alloc((size_t)128 * 1024 * 2);
    u16*   W52p = (u16*)  alloc((size_t)128 * 1024 * 2);
    float* b51p = (float*)alloc(512);
    float* b52p = (float*)alloc(512);
    float* b3c  = (float*)alloc(2048 * 4);
    u16*   bufA = (u16*)  alloc((size_t)B * 2048 * 2);   // h1 -> h31||h32
    u16*   bufB = (u16*)  alloc((size_t)B * 2048 * 2);   // h2 -> h41||h42
    u16*   bufC = (u16*)  alloc((size_t)B * 256 * 2);    // x51b | x52b
    u16* x51b = bufC;
    u16* x52b = bufC + (size_t)B * 128;
    const u16* NUL = nullptr;

    // stage-1 prep: W2 conversion + layer 1 (gates L2)
    k_prep1<<<5120, 256, 0, stream>>>(W2, W2b, x, W1, b1, bufA);

    // L2: h2 = relu(h1 @ W2^T + b2)  [B,2048] -> bufB
    // grid: 16 x (128 GEMM y-groups + 401 backfill rows = 6416 prep blocks)
    k_gemm_pl<<<dim3(16, 128 + 401), 256, 0, stream>>>(
        bufA, W2b, b2, bufB, 2048, 2048, 2048, 1, 128,
        NUL, NUL, nullptr, nullptr, 0,
        W31, W31b, W32, W32b, W41, W41b, W42, W42b,
        W51, W51p, b51, b51p, W52, W52p, b52, b52p, b31, b32, b3c);
    // L3 fused: h31||h32 = relu(h2 @ [W31;W32]^T + b3c) -> bufA
    k_gemm_pl<<<dim3(16, 128), 256, 0, stream>>>(
        bufB, W31b, b3c, bufA, 2048, 2048, 2048, 1, 128,
        NUL, NUL, nullptr, nullptr, 0,
        nullptr, nullptr, nullptr, nullptr, nullptr, nullptr, nullptr, nullptr,
        nullptr, nullptr, nullptr, nullptr, nullptr, nullptr, nullptr, nullptr,
        nullptr, nullptr, nullptr);
    // L4 fused: h41 -> bufB[:, :1024], h42 -> bufB[:, 1024:]
    k_gemm_pl<<<dim3(8, 256), 256, 0, stream>>>(
        bufA, W41b, b41, bufB, 1024, 2048, 2048, 1, 256,
        bufA + 1024, W42b, b42, bufB + 1024, 128,
        nullptr, nullptr, nullptr, nullptr, nullptr, nullptr, nullptr, nullptr,
        nullptr, nullptr, nullptr, nullptr, nullptr, nullptr, nullptr, nullptr,
        nullptr, nullptr, nullptr);
    // heads fused: x51b = h41 @ W51p^T; x52b = h42 @ W52p^T
    k_gemm_pl<<<dim3(1, 256), 256, 0, stream>>>(
        bufB, W51p, b51p, x51b, 1024, 2048, 128, 0, 256,
        bufB + 1024, W52p, b52p, x52b, 128,
        nullptr, nullptr, nullptr, nullptr, nullptr, nullptr, nullptr, nullptr,
        nullptr, nullptr, nullptr, nullptr, nullptr, nullptr, nullptr, nullptr,
        nullptr, nullptr, nullptr);

    // final physics + QP + combine
    k_final<<<B / 256, 256, 0, stream>>>(x51b, x52b, x, mean, std_,
                                         mean_label, std_label, wt, (float*)d_out);
}

// Round 8
// 504.459 us; speedup vs baseline: 1.2541x; 1.2541x over previous
//
#include <hip/hip_runtime.h>

typedef unsigned short u16;
typedef unsigned int   u32;
typedef __attribute__((ext_vector_type(8)))  short short8;   // 8 bf16 (4 VGPRs)
typedef __attribute__((ext_vector_type(16))) float floatx16; // 32x32 MFMA C/D
typedef __attribute__((ext_vector_type(8)))  u16   u16x8;
typedef __attribute__((ext_vector_type(4)))  u16   u16x4;

__device__ __forceinline__ u16 f2b(float f) {
    u32 u = __float_as_uint(f);
    u = (u + 0x7FFFu + ((u >> 16) & 1u)) >> 16;
    return (u16)u;
}
__device__ __forceinline__ float b2f(u16 h) {
    return __uint_as_float(((u32)h) << 16);
}

// ================= prep building blocks (256-thread granularity) ===========
__device__ __forceinline__ void f2b_block(const float* __restrict__ src,
                                          u16* __restrict__ dst, int blk) {
    int i = blk * 256 + threadIdx.x;
    float4 v = ((const float4*)src)[i];
    u16x4 o;
    o[0] = f2b(v.x); o[1] = f2b(v.y); o[2] = f2b(v.z); o[3] = f2b(v.w);
    *(u16x4*)&dst[i * 4] = o;
}

__device__ __forceinline__ void pad_block(const float* __restrict__ Wsrc, int rows,
                                          u16* __restrict__ Wdst,
                                          const float* __restrict__ bsrc,
                                          float* __restrict__ bdst, int blk) {
    int i = blk * 256 + threadIdx.x;        // 32768 total (128x1024/4)
    int idx = i * 4;
    int r = idx >> 10;
    int c = idx & 1023;
    u16x4 o;
    if (r < rows) {
        float4 v = *(const float4*)&Wsrc[r * 1024 + c];
        o[0] = f2b(v.x); o[1] = f2b(v.y); o[2] = f2b(v.z); o[3] = f2b(v.w);
    } else {
        o[0] = 0; o[1] = 0; o[2] = 0; o[3] = 0;
    }
    *(u16x4*)&Wdst[idx] = o;
    if (i < 128) bdst[i] = (i < rows) ? bsrc[i] : 0.f;
}

__device__ __forceinline__ void l1_block(const float* __restrict__ x,
                                         const float* __restrict__ W1,
                                         const float* __restrict__ b1,
                                         u16* __restrict__ h1, int blk) {
    const int t  = threadIdx.x;
    const int b0 = blk * 16;
    const int n0 = t * 8;
    float4 wreg[8]; float breg[8];
    const float4* W14 = (const float4*)W1;
#pragma unroll
    for (int i = 0; i < 8; ++i) { wreg[i] = W14[n0 + i]; breg[i] = b1[n0 + i]; }
    for (int r = 0; r < 16; ++r) {
        int b = b0 + r;
        float4 xv = ((const float4*)x)[b];
        u16x8 o;
#pragma unroll
        for (int i = 0; i < 8; ++i) {
            float s = xv.x * wreg[i].x + xv.y * wreg[i].y +
                      xv.z * wreg[i].z + xv.w * wreg[i].w + breg[i];
            s = fmaxf(s, 0.f);
            o[i] = f2b(s);
        }
        *(u16x8*)&h1[(size_t)b * 2048 + n0] = o;
    }
}

// ===== stage-1 prep: only what gates the L2 GEMM (W2 convert + layer 1) ====
__global__ __launch_bounds__(256)
void k_prep1(const float* W2, u16* W2b,
             const float* x, const float* W1, const float* b1, u16* h1) {
    int blk = blockIdx.x;
    if (blk < 4096) { f2b_block(W2, W2b, blk); return; }
    l1_block(x, W1, b1, h1, blk - 4096);
}

// ===== backfill prep (extra blocks inside the L2 GEMM dispatch) ============
__device__ __forceinline__ void backfill_prep(
        int pblk,
        const float* W31, u16* W31b, const float* W32, u16* W32b,
        const float* W41, u16* W41b, const float* W42, u16* W42b,
        const float* W51, u16* W51p, const float* b51, float* b51p,
        const float* W52, u16* W52p, const float* b52, float* b52p,
        const float* b31, const float* b32, float* b3c) {
    if (pblk < 2048) { f2b_block(W31, W31b, pblk); return; }   pblk -= 2048;
    if (pblk < 2048) { f2b_block(W32, W32b, pblk); return; }   pblk -= 2048;
    if (pblk < 1024) { f2b_block(W41, W41b, pblk); return; }   pblk -= 1024;
    if (pblk < 1024) { f2b_block(W42, W42b, pblk); return; }   pblk -= 1024;
    if (pblk < 128)  { pad_block(W51, 20, W51p, b51, b51p, pblk); return; } pblk -= 128;
    if (pblk < 128)  { pad_block(W52, 11, W52p, b52, b52p, pblk); return; } pblk -= 128;
    if (pblk < 8) {
        int i = pblk * 256 + threadIdx.x;
        b3c[i] = (i < 1024) ? b31[i] : b32[i - 1024];
    }
}

// ================= trunk bf16 MFMA GEMM: 256x128 tile, BK=64 (R6 best) =====
// C[M,N] = act(A[M,K] @ W[N,K]^T + b). 256 threads = 4 waves; wave tile
// 128x64 via 4x2 of mfma_f32_32x32x16_bf16, 4 k-steps -> 32 MFMA and
// 24 ds_read_b128 per wave per barrier. global_load_lds 16B/lane staging;
// XOR chunk swizzle (physical chunk p at row r holds logical p ^ (r&7)).
// XCD-aware swizzle over the GEMM portion; blocks beyond gemmY rows run
// backfill weight-prep (L2 dispatch only). Second GEMM via split.
__global__ __launch_bounds__(256, 2)
void k_gemm256(const u16* __restrict__ A, const u16* __restrict__ W,
               const float* __restrict__ bias, u16* __restrict__ C,
               int K, int lda, int ldc, int relu, int gemmY,
               const u16* A2, const u16* W2g, const float* bias2, u16* C2,
               int split,
               const float* W31, u16* W31b, const float* W32, u16* W32b,
               const float* W41, u16* W41b, const float* W42, u16* W42b,
               const float* W51, u16* W51p, const float* b51, float* b51p,
               const float* W52, u16* W52p, const float* b52, float* b52p,
               const float* b31, const float* b32, float* b3c) {
    const int ngemm = gemmY * gridDim.x;
    int flat = blockIdx.y * gridDim.x + blockIdx.x;
    if (flat >= ngemm) {
        backfill_prep(flat - ngemm, W31, W31b, W32, W32b, W41, W41b,
                      W42, W42b, W51, W51p, b51, b51p, W52, W52p, b52, b52p,
                      b31, b32, b3c);
        return;
    }

    __shared__ __align__(16) u16 As[256 * 64];  // 32 KB
    __shared__ __align__(16) u16 Ws[128 * 64];  // 16 KB

    const int tid  = threadIdx.x;
    const int wave = tid >> 6;
    const int lane = tid & 63;

    // XCD swizzle (valid permutation when gemmY % 8 == 0)
    int xcd = flat & 7;
    int p   = flat >> 3;
    int bx  = p % gridDim.x;
    int by  = (p / gridDim.x) * 8 + xcd;

    if (A2 != nullptr && by >= split) {
        A = A2; W = W2g; bias = bias2; C = C2; by -= split;
    }
    const int bm = by * 256;
    const int bn = bx * 128;

    const int srow = lane >> 3;                    // 0..7
    const int sg   = ((lane & 7) ^ srow) * 8;      // swizzled global k-elem offset

    const int wm    = (wave & 1) * 128;
    const int wn    = (wave >> 1) * 64;
    const int row32 = lane & 31;
    const int half  = lane >> 5;

    floatx16 acc[4][2];
#pragma unroll
    for (int i = 0; i < 4; ++i)
#pragma unroll
        for (int j = 0; j < 2; ++j)
#pragma unroll
            for (int r = 0; r < 16; ++r) acc[i][j][r] = 0.f;

    for (int k0 = 0; k0 < K; k0 += 64) {
#pragma unroll
        for (int i = 0; i < 8; ++i) {
            int ci = wave * 8 + i;              // 32 chunks of 8 rows (A)
            int r  = ci * 8 + srow;
            const u16* ga = A + (size_t)(bm + r) * lda + k0 + sg;
            __builtin_amdgcn_global_load_lds(
                (const __attribute__((address_space(1))) void*)ga,
                (__attribute__((address_space(3))) void*)&As[ci * 512], 16, 0, 0);
        }
#pragma unroll
        for (int i = 0; i < 4; ++i) {
            int ci = wave * 4 + i;              // 16 chunks of 8 rows (W)
            int r  = ci * 8 + srow;
            const u16* gw = W + (size_t)(bn + r) * K + k0 + sg;
            __builtin_amdgcn_global_load_lds(
                (const __attribute__((address_space(1))) void*)gw,
                (__attribute__((address_space(3))) void*)&Ws[ci * 512], 16, 0, 0);
        }
        __syncthreads();

#pragma unroll
        for (int s = 0; s < 4; ++s) {
            const int c = s * 2 + half;         // logical 16B chunk 0..7
            short8 af[4], bf[2];
#pragma unroll
            for (int i = 0; i < 4; ++i) {
                int r = wm + i * 32 + row32;
                af[i] = *(const short8*)&As[r * 64 + ((c ^ (r & 7)) * 8)];
            }
#pragma unroll
            for (int j = 0; j < 2; ++j) {
                int r = wn + j * 32 + row32;
                bf[j] = *(const short8*)&Ws[r * 64 + ((c ^ (r & 7)) * 8)];
            }
#pragma unroll
            for (int i = 0; i < 4; ++i)
#pragma unroll
                for (int j = 0; j < 2; ++j)
                    acc[i][j] = __builtin_amdgcn_mfma_f32_32x32x16_bf16(
                        af[i], bf[j], acc[i][j], 0, 0, 0);
        }
        __syncthreads();
    }

    // epilogue: C/D layout col=lane&31, row=(reg&3)+8*(reg>>2)+4*(lane>>5)
    float bv[2];
#pragma unroll
    for (int j = 0; j < 2; ++j) bv[j] = bias[bn + wn + j * 32 + row32];
#pragma unroll
    for (int i = 0; i < 4; ++i)
#pragma unroll
        for (int j = 0; j < 2; ++j)
#pragma unroll
            for (int r = 0; r < 16; ++r) {
                int row = bm + wm + i * 32 + (r & 3) + 8 * (r >> 2) + 4 * half;
                int col = bn + wn + j * 32 + row32;
                float v = acc[i][j][r] + bv[j];
                if (relu) v = fmaxf(v, 0.f);
                C[(size_t)row * ldc + col] = f2b(v);
            }
}

// ====== fused heads + physics/QP/softmax epilogue ==========================
// 128 blocks x 256 threads; block owns 128 batch rows. Runs two K=1024
// GEMMs (x51 = h41 @ W51p^T + b51p into LDS[128][20]; x52 = h42 @ W52p^T
// + b52p into LDS[128][11]), then the per-row QP epilogue — no bf16
// round-trip of head outputs through HBM, no separate k_final dispatch.
__global__ __launch_bounds__(256, 2)
void k_heads_final(const u16* __restrict__ hbuf,       // bufB: h41 || h42
                   const u16* __restrict__ W51p, const float* __restrict__ b51p,
                   const u16* __restrict__ W52p, const float* __restrict__ b52p,
                   const float* __restrict__ x, const float* __restrict__ mean,
                   const float* __restrict__ std_,
                   const float* __restrict__ mean_label,
                   const float* __restrict__ std_label,
                   const float* __restrict__ wt, float* __restrict__ out) {
    __shared__ __align__(16) u16 As[128 * 64];     // 16 KB
    __shared__ __align__(16) u16 Ws[128 * 64];     // 16 KB
    __shared__ float x51s[128 * 20];               // 10 KB
    __shared__ float x52s[128 * 11];               // 5.5 KB

    const int tid  = threadIdx.x;
    const int wave = tid >> 6;
    const int lane = tid & 63;
    const int bm   = blockIdx.x * 128;

    const int srow = lane >> 3;
    const int sg   = ((lane & 7) ^ srow) * 8;

    const int wm    = (wave & 1) * 64;
    const int wn    = (wave >> 1) * 64;
    const int row32 = lane & 31;
    const int half  = lane >> 5;

    auto run_gemm = [&](const u16* Abase, const u16* Wp, const float* bp,
                        float* dst, int ncols) {
        floatx16 acc[2][2];
#pragma unroll
        for (int i = 0; i < 2; ++i)
#pragma unroll
            for (int j = 0; j < 2; ++j)
#pragma unroll
                for (int r = 0; r < 16; ++r) acc[i][j][r] = 0.f;

        for (int k0 = 0; k0 < 1024; k0 += 64) {
#pragma unroll
            for (int i = 0; i < 4; ++i) {
                int ci = wave * 4 + i;
                int r  = ci * 8 + srow;
                const u16* ga = Abase + (size_t)(bm + r) * 2048 + k0 + sg;
                __builtin_amdgcn_global_load_lds(
                    (const __attribute__((address_space(1))) void*)ga,
                    (__attribute__((address_space(3))) void*)&As[ci * 512], 16, 0, 0);
                const u16* gw = Wp + (size_t)r * 1024 + k0 + sg;
                __builtin_amdgcn_global_load_lds(
                    (const __attribute__((address_space(1))) void*)gw,
                    (__attribute__((address_space(3))) void*)&Ws[ci * 512], 16, 0, 0);
            }
            __syncthreads();
#pragma unroll
            for (int s = 0; s < 4; ++s) {
                const int c = s * 2 + half;
                short8 a0, a1, b0, b1;
                { int r = wm + row32;       a0 = *(const short8*)&As[r * 64 + ((c ^ (r & 7)) * 8)]; }
                { int r = wm + 32 + row32;  a1 = *(const short8*)&As[r * 64 + ((c ^ (r & 7)) * 8)]; }
                { int r = wn + row32;       b0 = *(const short8*)&Ws[r * 64 + ((c ^ (r & 7)) * 8)]; }
                { int r = wn + 32 + row32;  b1 = *(const short8*)&Ws[r * 64 + ((c ^ (r & 7)) * 8)]; }
                acc[0][0] = __builtin_amdgcn_mfma_f32_32x32x16_bf16(a0, b0, acc[0][0], 0, 0, 0);
                acc[0][1] = __builtin_amdgcn_mfma_f32_32x32x16_bf16(a0, b1, acc[0][1], 0, 0, 0);
                acc[1][0] = __builtin_amdgcn_mfma_f32_32x32x16_bf16(a1, b0, acc[1][0], 0, 0, 0);
                acc[1][1] = __builtin_amdgcn_mfma_f32_32x32x16_bf16(a1, b1, acc[1][1], 0, 0, 0);
            }
            __syncthreads();
        }
        // extract only the needed columns into LDS (fp32, bias added)
#pragma unroll
        for (int i = 0; i < 2; ++i)
#pragma unroll
            for (int j = 0; j < 2; ++j) {
                int col = wn + j * 32 + row32;
                if (col < ncols) {
                    float bj = bp[col];
#pragma unroll
                    for (int r = 0; r < 16; ++r) {
                        int row = wm + i * 32 + (r & 3) + 8 * (r >> 2) + 4 * half;
                        dst[row * ncols + col] = acc[i][j][r] + bj;
                    }
                }
            }
    };

    run_gemm(hbuf,        W51p, b51p, x51s, 20);   // x51 (heads ref)
    run_gemm(hbuf + 1024, W52p, b52p, x52s, 11);   // x52 (alpha/betas pre-sigmoid)
    __syncthreads();

    if (tid < 128) {
        int b = bm + tid;

        float w[10], m = -1e30f;
#pragma unroll
        for (int h = 0; h < 10; ++h) { w[h] = wt[h]; m = fmaxf(m, w[h]); }
        float ssum = 0.f;
#pragma unroll
        for (int h = 0; h < 10; ++h) { w[h] = __expf(w[h] - m); ssum += w[h]; }
        float winv = 1.f / ssum;

        float4 xv = ((const float4*)x)[b];
        float th1 = xv.x * std_[0] + mean[0];
        float w1v = xv.y * std_[1] + mean[1];
        float th2 = xv.z * std_[2] + mean[2];
        float w2v = xv.w * std_[3] + mean[3];
        float s1 = sinf(th1), c1 = cosf(th1);
        float s2 = sinf(th2), c2 = cosf(th2);
        float px = 3.f * c1 + 3.f * c2 - 0.f;
        float py = 3.f * s1 + 3.f * s2 - 7.f;
        float vx = -3.f * s1 * w1v - 3.f * s2 * w2v;
        float vy =  3.f * c1 * w1v + 3.f * c2 * w2v;
        float barrier = px * px + py * py - 16.f;
        float b_dot = 2.f * (px * vx + py * vy);
        float Lf2b = 2.f * vx * vx + 2.f * vy * vy
                   + 2.f * px * (-3.f * c1 * w1v * w1v - 3.f * c2 * w2v * w2v)
                   + 2.f * py * (-3.f * s1 * w1v * w1v - 3.f * s2 * w2v * w2v);
        float g1 = 2.f * px * (-3.f * s1) + 2.f * py * (3.f * c1);
        float g2 = 2.f * px * (-3.f * s2) + 2.f * py * (3.f * c2);
        float Gx = -g1, Gy = -g2;
        float Gdot = Gx * Gx + Gy * Gy;

        float alpha = 4.f / (1.f + expf(-x52s[tid * 11 + 0]));

        float rx = 0.f, ry = 0.f;
#pragma unroll
        for (int h = 0; h < 10; ++h) {
            float r0 = x51s[tid * 20 + 2 * h];
            float r1 = x51s[tid * 20 + 2 * h + 1];
            float beta = 4.f / (1.f + expf(-x52s[tid * 11 + 1 + h]));
            float hh = Lf2b + (alpha + beta) * b_dot + alpha * beta * barrier;
            float ux = -r0, uy = -r1;
            float viol = ux * Gx + uy * Gy - hh;
            float lam = fmaxf(viol / Gdot, 0.f);
            float sx = ux - lam * Gx;
            float sy = uy - lam * Gy;
            float wk = w[h] * winv;
            rx += wk * sx; ry += wk * sy;
        }
        out[2 * b]     = (rx - mean_label[0]) / std_label[0];
        out[2 * b + 1] = (ry - mean_label[1]) / std_label[1];
    }
}

extern "C" void kernel_launch(void* const* d_in, const int* in_sizes, int n_in,
                              void* d_out, int out_size, void* d_ws, size_t ws_size,
                              hipStream_t stream) {
    const float* x    = (const float*)d_in[0];
    const float* mean = (const float*)d_in[2];
    const float* std_ = (const float*)d_in[3];
    const float* mean_label = (const float*)d_in[4];
    const float* std_label  = (const float*)d_in[5];
    const float* W1  = (const float*)d_in[6];
    const float* b1  = (const float*)d_in[7];
    const float* W2  = (const float*)d_in[8];
    const float* b2  = (const float*)d_in[9];
    const float* W31 = (const float*)d_in[10];
    const float* b31 = (const float*)d_in[11];
    const float* W32 = (const float*)d_in[12];
    const float* b32 = (const float*)d_in[13];
    const float* W41 = (const float*)d_in[14];
    const float* b41 = (const float*)d_in[15];
    const float* W42 = (const float*)d_in[16];
    const float* b42 = (const float*)d_in[17];
    const float* W51 = (const float*)d_in[18];
    const float* b51 = (const float*)d_in[19];
    const float* W52 = (const float*)d_in[20];
    const float* b52 = (const float*)d_in[21];
    const float* wt  = (const float*)d_in[22];

    const int B = in_sizes[0] / 4;       // 16384

    char* wsp = (char*)d_ws;
    size_t off = 0;
    auto alloc = [&](size_t bytes) {
        void* p = wsp + off;
        off += (bytes + 255) & ~(size_t)255;
        return p;
    };
    u16*   W2b  = (u16*)  alloc((size_t)2048 * 2048 * 2);
    u16*   W31b = (u16*)  alloc((size_t)1024 * 2048 * 2);  // W31b||W32b contiguous
    u16*   W32b = (u16*)  alloc((size_t)1024 * 2048 * 2);  //   = [2048][2048] weight
    u16*   W41b = (u16*)  alloc((size_t)1024 * 1024 * 2);
    u16*   W42b = (u16*)  alloc((size_t)1024 * 1024 * 2);
    u16*   W51p = (u16*)  alloc((size_t)128 * 1024 * 2);
    u16*   W52p = (u16*)  alloc((size_t)128 * 1024 * 2);
    float* b51p = (float*)alloc(512);
    float* b52p = (float*)alloc(512);
    float* b3c  = (float*)alloc(2048 * 4);
    u16*   bufA = (u16*)  alloc((size_t)B * 2048 * 2);   // h1 -> h31||h32
    u16*   bufB = (u16*)  alloc((size_t)B * 2048 * 2);   // h2 -> h41||h42
    const u16* NUL = nullptr;

    // stage-1 prep: W2 conversion + layer 1 (gates L2)
    k_prep1<<<5120, 256, 0, stream>>>(W2, W2b, x, W1, b1, bufA);

    // L2: h2 = relu(h1 @ W2^T + b2)  [B,2048] -> bufB
    // grid: 16 x (64 GEMM y-groups + 401 backfill rows = 6416 prep blocks)
    k_gemm256<<<dim3(16, 64 + 401), 256, 0, stream>>>(
        bufA, W2b, b2, bufB, 2048, 2048, 2048, 1, 64,
        NUL, NUL, nullptr, nullptr, 0,
        W31, W31b, W32, W32b, W41, W41b, W42, W42b,
        W51, W51p, b51, b51p, W52, W52p, b52, b52p, b31, b32, b3c);
    // L3 fused: h31||h32 = relu(h2 @ [W31;W32]^T + b3c) -> bufA
    k_gemm256<<<dim3(16, 64), 256, 0, stream>>>(
        bufB, W31b, b3c, bufA, 2048, 2048, 2048, 1, 64,
        NUL, NUL, nullptr, nullptr, 0,
        nullptr, nullptr, nullptr, nullptr, nullptr, nullptr, nullptr, nullptr,
        nullptr, nullptr, nullptr, nullptr, nullptr, nullptr, nullptr, nullptr,
        nullptr, nullptr, nullptr);
    // L4 fused: h41 -> bufB[:, :1024], h42 -> bufB[:, 1024:]
    k_gemm256<<<dim3(8, 128), 256, 0, stream>>>(
        bufA, W41b, b41, bufB, 1024, 2048, 2048, 1, 128,
        bufA + 1024, W42b, b42, bufB + 1024, 64,
        nullptr, nullptr, nullptr, nullptr, nullptr, nullptr, nullptr, nullptr,
        nullptr, nullptr, nullptr, nullptr, nullptr, nullptr, nullptr, nullptr,
        nullptr, nullptr, nullptr);
    // fused heads GEMMs + physics/QP/softmax epilogue
    k_heads_final<<<B / 128, 256, 0, stream>>>(
        bufB, W51p, b51p, W52p, b52p, x, mean, std_,
        mean_label, std_label, wt, (float*)d_out);
}

// Round 9
// 456.442 us; speedup vs baseline: 1.3860x; 1.1052x over previous
//
#include <hip/hip_runtime.h>

typedef unsigned short u16;
typedef unsigned char  u8;
typedef unsigned int   u32;
typedef __attribute__((ext_vector_type(8)))  short short8;   // 8 bf16 (4 VGPRs)
typedef __attribute__((ext_vector_type(16))) float floatx16; // 32x32 MFMA C/D f32
typedef __attribute__((ext_vector_type(4)))  int   intx4;    // 16 i8 (4 VGPRs)
typedef __attribute__((ext_vector_type(16))) int   intx16;   // 32x32 i8 MFMA C/D
typedef __attribute__((ext_vector_type(8)))  u16   u16x8;
typedef __attribute__((ext_vector_type(4)))  u16   u16x4;

__device__ __forceinline__ u16 f2b(float f) {
    u32 u = __float_as_uint(f);
    u = (u + 0x7FFFu + ((u >> 16) & 1u)) >> 16;
    return (u16)u;
}
__device__ __forceinline__ float b2f(u16 h) {
    return __uint_as_float(((u32)h) << 16);
}
__device__ __forceinline__ int q8(float v, float inv) {
    return __float2int_rn(fminf(fmaxf(v * inv, -127.f), 127.f));
}

// ================= prep building blocks (256-thread granularity) ===========
__device__ __forceinline__ void f2b_block(const float* __restrict__ src,
                                          u16* __restrict__ dst, int blk) {
    int i = blk * 256 + threadIdx.x;
    float4 v = ((const float4*)src)[i];
    u16x4 o;
    o[0] = f2b(v.x); o[1] = f2b(v.y); o[2] = f2b(v.z); o[3] = f2b(v.w);
    *(u16x4*)&dst[i * 4] = o;
}

__device__ __forceinline__ void pad_block(const float* __restrict__ Wsrc, int rows,
                                          u16* __restrict__ Wdst,
                                          const float* __restrict__ bsrc,
                                          float* __restrict__ bdst, int blk) {
    int i = blk * 256 + threadIdx.x;        // 32768 total (128x1024/4)
    int idx = i * 4;
    int r = idx >> 10;
    int c = idx & 1023;
    u16x4 o;
    if (r < rows) {
        float4 v = *(const float4*)&Wsrc[r * 1024 + c];
        o[0] = f2b(v.x); o[1] = f2b(v.y); o[2] = f2b(v.z); o[3] = f2b(v.w);
    } else {
        o[0] = 0; o[1] = 0; o[2] = 0; o[3] = 0;
    }
    *(u16x4*)&Wdst[idx] = o;
    if (i < 128) bdst[i] = (i < rows) ? bsrc[i] : 0.f;
}

// ---- W row-quant: one wave per row. Wq[n,k]=rint(W/sw), sw=rowmax/127,
// ---- Wsum[n]=sw*sum(q) for the asymmetric-A correction term.
__device__ __forceinline__ void wquant_row(const float* __restrict__ Wsrc, int K,
                                           u8* __restrict__ Wq, float* __restrict__ sW,
                                           float* __restrict__ Wsum, int row) {
    const int lane = threadIdx.x & 63;
    const float* src = Wsrc + (size_t)row * K;
    const int iters = K >> 8;               // 256 floats per iter (64 lanes x float4)
    float mx = 0.f;
    for (int i = 0; i < iters; ++i) {
        float4 v = *(const float4*)&src[i * 256 + lane * 4];
        mx = fmaxf(mx, fmaxf(fmaxf(fabsf(v.x), fabsf(v.y)),
                             fmaxf(fabsf(v.z), fabsf(v.w))));
    }
#pragma unroll
    for (int off = 32; off >= 1; off >>= 1) mx = fmaxf(mx, __shfl_xor(mx, off));
    float sw  = fmaxf(mx * (1.f / 127.f), 1e-20f);
    float inv = 1.f / sw;
    int ssum = 0;
    for (int i = 0; i < iters; ++i) {
        float4 v = *(const float4*)&src[i * 256 + lane * 4];
        int q0 = q8(v.x, inv), q1 = q8(v.y, inv), q2 = q8(v.z, inv), q3 = q8(v.w, inv);
        ssum += q0 + q1 + q2 + q3;
        u32 p = (q0 & 255) | ((q1 & 255) << 8) | ((q2 & 255) << 16) | ((q3 & 255) << 24);
        *(u32*)&Wq[(size_t)row * K + i * 256 + lane * 4] = p;
    }
#pragma unroll
    for (int off = 32; off >= 1; off >>= 1) ssum += __shfl_xor(ssum, off);
    if (lane == 0) { sW[row] = sw; Wsum[row] = sw * (float)ssum; }
}

// ---- layer 1 + per-row asymmetric i8 quant of h1 ----
__device__ __forceinline__ void l1q_block(const float* __restrict__ x,
                                          const float* __restrict__ W1,
                                          const float* __restrict__ b1,
                                          u8* __restrict__ h1q,
                                          float* __restrict__ sA,
                                          float* __restrict__ muA, int blk) {
    __shared__ float wmx[4], wmn[4];
    const int t    = threadIdx.x;
    const int wave = t >> 6;
    const int lane = t & 63;
    const int b0 = blk * 16;
    const int n0 = t * 8;
    float4 wreg[8]; float breg[8];
    const float4* W14 = (const float4*)W1;
#pragma unroll
    for (int i = 0; i < 8; ++i) { wreg[i] = W14[n0 + i]; breg[i] = b1[n0 + i]; }
    for (int r = 0; r < 16; ++r) {
        int b = b0 + r;
        float4 xv = ((const float4*)x)[b];
        float v[8];
        float lmx = 0.f, lmn = 3.4e38f;
#pragma unroll
        for (int i = 0; i < 8; ++i) {
            float s = xv.x * wreg[i].x + xv.y * wreg[i].y +
                      xv.z * wreg[i].z + xv.w * wreg[i].w + breg[i];
            s = fmaxf(s, 0.f);
            v[i] = s;
            lmx = fmaxf(lmx, s); lmn = fminf(lmn, s);
        }
#pragma unroll
        for (int off = 32; off >= 1; off >>= 1) {
            lmx = fmaxf(lmx, __shfl_xor(lmx, off));
            lmn = fminf(lmn, __shfl_xor(lmn, off));
        }
        if (lane == 0) { wmx[wave] = lmx; wmn[wave] = lmn; }
        __syncthreads();
        float mx = fmaxf(fmaxf(wmx[0], wmx[1]), fmaxf(wmx[2], wmx[3]));
        float mn = fminf(fminf(wmn[0], wmn[1]), fminf(wmn[2], wmn[3]));
        float mu  = 0.5f * (mx + mn);
        float s   = fmaxf((mx - mn) * (1.f / 254.f), 1e-20f);
        float inv = 1.f / s;
        int q[8];
#pragma unroll
        for (int i = 0; i < 8; ++i) q[i] = q8(v[i] - mu, inv);
        uint2 p;
        p.x = (q[0] & 255) | ((q[1] & 255) << 8) | ((q[2] & 255) << 16) | ((q[3] & 255) << 24);
        p.y = (q[4] & 255) | ((q[5] & 255) << 8) | ((q[6] & 255) << 16) | ((q[7] & 255) << 24);
        *(uint2*)&h1q[(size_t)b * 2048 + n0] = p;
        if (t == 0) { sA[b] = s; muA[b] = mu; }
        __syncthreads();
    }
}

// ===== stage-1 prep: W2 row-quant (512 blocks, 4 rows each) + l1q (1024) ===
__global__ __launch_bounds__(256)
void k_prep1(const float* W2, u8* W2q, float* sW2, float* Wsum2,
             const float* x, const float* W1, const float* b1,
             u8* h1q, float* sA1, float* muA1) {
    int blk = blockIdx.x;
    if (blk < 512) {
        wquant_row(W2, 2048, W2q, sW2, Wsum2, blk * 4 + (threadIdx.x >> 6));
        return;
    }
    l1q_block(x, W1, b1, h1q, sA1, muA1, blk - 512);
}

// ===== backfill prep (extra blocks inside the L2 GEMM dispatch) ============
__device__ __forceinline__ void backfill_prep(
        int pblk,
        const float* W31, u16* W31b, const float* W32, u16* W32b,
        const float* W41, u16* W41b, const float* W42, u16* W42b,
        const float* W51, u16* W51p, const float* b51, float* b51p,
        const float* W52, u16* W52p, const float* b52, float* b52p,
        const float* b31, const float* b32, float* b3c) {
    if (pblk < 2048) { f2b_block(W31, W31b, pblk); return; }   pblk -= 2048;
    if (pblk < 2048) { f2b_block(W32, W32b, pblk); return; }   pblk -= 2048;
    if (pblk < 1024) { f2b_block(W41, W41b, pblk); return; }   pblk -= 1024;
    if (pblk < 1024) { f2b_block(W42, W42b, pblk); return; }   pblk -= 1024;
    if (pblk < 128)  { pad_block(W51, 20, W51p, b51, b51p, pblk); return; } pblk -= 128;
    if (pblk < 128)  { pad_block(W52, 11, W52p, b52, b52p, pblk); return; } pblk -= 128;
    if (pblk < 8) {
        int i = pblk * 256 + threadIdx.x;
        b3c[i] = (i < 1024) ? b31[i] : b32[i - 1024];
    }
}

// ================= i8 MFMA GEMM: 256x128 tile, BK=128 i8 ===================
// C[M,N] = act(dequant(Aq @ Wq^T) + b), A per-row asymmetric (mu,s), W
// per-row symmetric (sW, Wsum = sW*sum(q)). Byte geometry identical to the
// bf16 kernel (128 B rows, 16 B chunks, XOR swizzle); 16 K-iters for K=2048.
// mfma_i32_32x32x32_i8: lane row=lane&31, k=(lane>>5)*16+[0..16) per k-32
// window (natural doubling of the verified bf16 32x32x16 pattern).
// Epilogue: v = accI*(sA*sW) + muA*Wsum + bias. Backfill blocks beyond gemmY.
__global__ __launch_bounds__(256, 2)
void k_gemmq(const u8* __restrict__ A, const u8* __restrict__ Wq,
             const float* __restrict__ sA, const float* __restrict__ muA,
             const float* __restrict__ sW, const float* __restrict__ Wsum,
             const float* __restrict__ bias, u16* __restrict__ C,
             int K, int ldc, int relu, int gemmY,
             const float* W31, u16* W31b, const float* W32, u16* W32b,
             const float* W41, u16* W41b, const float* W42, u16* W42b,
             const float* W51, u16* W51p, const float* b51, float* b51p,
             const float* W52, u16* W52p, const float* b52, float* b52p,
             const float* b31, const float* b32, float* b3c) {
    const int ngemm = gemmY * gridDim.x;
    int flat = blockIdx.y * gridDim.x + blockIdx.x;
    if (flat >= ngemm) {
        backfill_prep(flat - ngemm, W31, W31b, W32, W32b, W41, W41b,
                      W42, W42b, W51, W51p, b51, b51p, W52, W52p, b52, b52p,
                      b31, b32, b3c);
        return;
    }

    __shared__ __align__(16) u8 As[256 * 128];  // 32 KB
    __shared__ __align__(16) u8 Ws[128 * 128];  // 16 KB

    const int tid  = threadIdx.x;
    const int wave = tid >> 6;
    const int lane = tid & 63;

    int xcd = flat & 7;
    int p   = flat >> 3;
    int bx  = p % gridDim.x;
    int by  = (p / gridDim.x) * 8 + xcd;
    const int bm = by * 256;
    const int bn = bx * 128;

    const int srow = lane >> 3;                     // 0..7
    const int sg   = ((lane & 7) ^ srow) * 16;      // swizzled global byte offset

    const int wm    = (wave & 1) * 128;
    const int wn    = (wave >> 1) * 64;
    const int row32 = lane & 31;
    const int half  = lane >> 5;

    intx16 acc[4][2];
#pragma unroll
    for (int i = 0; i < 4; ++i)
#pragma unroll
        for (int j = 0; j < 2; ++j)
#pragma unroll
            for (int r = 0; r < 16; ++r) acc[i][j][r] = 0;

    for (int k0 = 0; k0 < K; k0 += 128) {
#pragma unroll
        for (int i = 0; i < 8; ++i) {
            int ci = wave * 8 + i;              // 32 chunks of 8 rows (A)
            int r  = ci * 8 + srow;
            const u8* ga = A + (size_t)(bm + r) * K + k0 + sg;
            __builtin_amdgcn_global_load_lds(
                (const __attribute__((address_space(1))) void*)ga,
                (__attribute__((address_space(3))) void*)&As[ci * 1024], 16, 0, 0);
        }
#pragma unroll
        for (int i = 0; i < 4; ++i) {
            int ci = wave * 4 + i;              // 16 chunks of 8 rows (W)
            int r  = ci * 8 + srow;
            const u8* gw = Wq + (size_t)(bn + r) * K + k0 + sg;
            __builtin_amdgcn_global_load_lds(
                (const __attribute__((address_space(1))) void*)gw,
                (__attribute__((address_space(3))) void*)&Ws[ci * 1024], 16, 0, 0);
        }
        __syncthreads();

#pragma unroll
        for (int s = 0; s < 4; ++s) {
            const int c = s * 2 + half;         // logical 16B chunk 0..7
            intx4 af[4], bf[2];
#pragma unroll
            for (int i = 0; i < 4; ++i) {
                int r = wm + i * 32 + row32;
                af[i] = *(const intx4*)&As[r * 128 + ((c ^ (r & 7)) * 16)];
            }
#pragma unroll
            for (int j = 0; j < 2; ++j) {
                int r = wn + j * 32 + row32;
                bf[j] = *(const intx4*)&Ws[r * 128 + ((c ^ (r & 7)) * 16)];
            }
#pragma unroll
            for (int i = 0; i < 4; ++i)
#pragma unroll
                for (int j = 0; j < 2; ++j)
                    acc[i][j] = __builtin_amdgcn_mfma_i32_32x32x32_i8(
                        af[i], bf[j], acc[i][j], 0, 0, 0);
        }
        __syncthreads();
    }

    // epilogue: dequant. C/D layout col=lane&31, row=(r&3)+8*(r>>2)+4*half
    float sWv[2], Wsv[2], bv[2];
#pragma unroll
    for (int j = 0; j < 2; ++j) {
        int col = bn + wn + j * 32 + row32;
        sWv[j] = sW[col]; Wsv[j] = Wsum[col]; bv[j] = bias[col];
    }
#pragma unroll
    for (int i = 0; i < 4; ++i)
#pragma unroll
        for (int r = 0; r < 16; ++r) {
            int row = bm + wm + i * 32 + (r & 3) + 8 * (r >> 2) + 4 * half;
            float sa = sA[row], mu = muA[row];
#pragma unroll
            for (int j = 0; j < 2; ++j) {
                int col = bn + wn + j * 32 + row32;
                float v = (float)acc[i][j][r] * (sa * sWv[j]) + mu * Wsv[j] + bv[j];
                if (relu) v = fmaxf(v, 0.f);
                C[(size_t)row * ldc + col] = f2b(v);
            }
        }
}

// ================= trunk bf16 MFMA GEMM: 256x128 tile, BK=64 (R6/R8) =======
__global__ __launch_bounds__(256, 2)
void k_gemm256(const u16* __restrict__ A, const u16* __restrict__ W,
               const float* __restrict__ bias, u16* __restrict__ C,
               int K, int lda, int ldc, int relu, int gemmY,
               const u16* A2, const u16* W2g, const float* bias2, u16* C2,
               int split) {
    __shared__ __align__(16) u16 As[256 * 64];  // 32 KB
    __shared__ __align__(16) u16 Ws[128 * 64];  // 16 KB

    const int tid  = threadIdx.x;
    const int wave = tid >> 6;
    const int lane = tid & 63;

    int flat = blockIdx.y * gridDim.x + blockIdx.x;
    int xcd = flat & 7;
    int p   = flat >> 3;
    int bx  = p % gridDim.x;
    int by  = (p / gridDim.x) * 8 + xcd;

    if (A2 != nullptr && by >= split) {
        A = A2; W = W2g; bias = bias2; C = C2; by -= split;
    }
    const int bm = by * 256;
    const int bn = bx * 128;

    const int srow = lane >> 3;
    const int sg   = ((lane & 7) ^ srow) * 8;

    const int wm    = (wave & 1) * 128;
    const int wn    = (wave >> 1) * 64;
    const int row32 = lane & 31;
    const int half  = lane >> 5;

    floatx16 acc[4][2];
#pragma unroll
    for (int i = 0; i < 4; ++i)
#pragma unroll
        for (int j = 0; j < 2; ++j)
#pragma unroll
            for (int r = 0; r < 16; ++r) acc[i][j][r] = 0.f;

    for (int k0 = 0; k0 < K; k0 += 64) {
#pragma unroll
        for (int i = 0; i < 8; ++i) {
            int ci = wave * 8 + i;
            int r  = ci * 8 + srow;
            const u16* ga = A + (size_t)(bm + r) * lda + k0 + sg;
            __builtin_amdgcn_global_load_lds(
                (const __attribute__((address_space(1))) void*)ga,
                (__attribute__((address_space(3))) void*)&As[ci * 512], 16, 0, 0);
        }
#pragma unroll
        for (int i = 0; i < 4; ++i) {
            int ci = wave * 4 + i;
            int r  = ci * 8 + srow;
            const u16* gw = W + (size_t)(bn + r) * K + k0 + sg;
            __builtin_amdgcn_global_load_lds(
                (const __attribute__((address_space(1))) void*)gw,
                (__attribute__((address_space(3))) void*)&Ws[ci * 512], 16, 0, 0);
        }
        __syncthreads();

#pragma unroll
        for (int s = 0; s < 4; ++s) {
            const int c = s * 2 + half;
            short8 af[4], bf[2];
#pragma unroll
            for (int i = 0; i < 4; ++i) {
                int r = wm + i * 32 + row32;
                af[i] = *(const short8*)&As[r * 64 + ((c ^ (r & 7)) * 8)];
            }
#pragma unroll
            for (int j = 0; j < 2; ++j) {
                int r = wn + j * 32 + row32;
                bf[j] = *(const short8*)&Ws[r * 64 + ((c ^ (r & 7)) * 8)];
            }
#pragma unroll
            for (int i = 0; i < 4; ++i)
#pragma unroll
                for (int j = 0; j < 2; ++j)
                    acc[i][j] = __builtin_amdgcn_mfma_f32_32x32x16_bf16(
                        af[i], bf[j], acc[i][j], 0, 0, 0);
        }
        __syncthreads();
    }

    float bv[2];
#pragma unroll
    for (int j = 0; j < 2; ++j) bv[j] = bias[bn + wn + j * 32 + row32];
#pragma unroll
    for (int i = 0; i < 4; ++i)
#pragma unroll
        for (int j = 0; j < 2; ++j)
#pragma unroll
            for (int r = 0; r < 16; ++r) {
                int row = bm + wm + i * 32 + (r & 3) + 8 * (r >> 2) + 4 * half;
                int col = bn + wn + j * 32 + row32;
                float v = acc[i][j][r] + bv[j];
                if (relu) v = fmaxf(v, 0.f);
                C[(size_t)row * ldc + col] = f2b(v);
            }
}

// ====== fused heads + physics/QP/softmax epilogue (unchanged from R8) ======
__global__ __launch_bounds__(256, 2)
void k_heads_final(const u16* __restrict__ hbuf,       // bufB: h41 || h42
                   const u16* __restrict__ W51p, const float* __restrict__ b51p,
                   const u16* __restrict__ W52p, const float* __restrict__ b52p,
                   const float* __restrict__ x, const float* __restrict__ mean,
                   const float* __restrict__ std_,
                   const float* __restrict__ mean_label,
                   const float* __restrict__ std_label,
                   const float* __restrict__ wt, float* __restrict__ out) {
    __shared__ __align__(16) u16 As[128 * 64];     // 16 KB
    __shared__ __align__(16) u16 Ws[128 * 64];     // 16 KB
    __shared__ float x51s[128 * 20];               // 10 KB
    __shared__ float x52s[128 * 11];               // 5.5 KB

    const int tid  = threadIdx.x;
    const int wave = tid >> 6;
    const int lane = tid & 63;
    const int bm   = blockIdx.x * 128;

    const int srow = lane >> 3;
    const int sg   = ((lane & 7) ^ srow) * 8;

    const int wm    = (wave & 1) * 64;
    const int wn    = (wave >> 1) * 64;
    const int row32 = lane & 31;
    const int half  = lane >> 5;

    auto run_gemm = [&](const u16* Abase, const u16* Wp, const float* bp,
                        float* dst, int ncols) {
        floatx16 acc[2][2];
#pragma unroll
        for (int i = 0; i < 2; ++i)
#pragma unroll
            for (int j = 0; j < 2; ++j)
#pragma unroll
                for (int r = 0; r < 16; ++r) acc[i][j][r] = 0.f;

        for (int k0 = 0; k0 < 1024; k0 += 64) {
#pragma unroll
            for (int i = 0; i < 4; ++i) {
                int ci = wave * 4 + i;
                int r  = ci * 8 + srow;
                const u16* ga = Abase + (size_t)(bm + r) * 2048 + k0 + sg;
                __builtin_amdgcn_global_load_lds(
                    (const __attribute__((address_space(1))) void*)ga,
                    (__attribute__((address_space(3))) void*)&As[ci * 512], 16, 0, 0);
                const u16* gw = Wp + (size_t)r * 1024 + k0 + sg;
                __builtin_amdgcn_global_load_lds(
                    (const __attribute__((address_space(1))) void*)gw,
                    (__attribute__((address_space(3))) void*)&Ws[ci * 512], 16, 0, 0);
            }
            __syncthreads();
#pragma unroll
            for (int s = 0; s < 4; ++s) {
                const int c = s * 2 + half;
                short8 a0, a1, b0, b1;
                { int r = wm + row32;       a0 = *(const short8*)&As[r * 64 + ((c ^ (r & 7)) * 8)]; }
                { int r = wm + 32 + row32;  a1 = *(const short8*)&As[r * 64 + ((c ^ (r & 7)) * 8)]; }
                { int r = wn + row32;       b0 = *(const short8*)&Ws[r * 64 + ((c ^ (r & 7)) * 8)]; }
                { int r = wn + 32 + row32;  b1 = *(const short8*)&Ws[r * 64 + ((c ^ (r & 7)) * 8)]; }
                acc[0][0] = __builtin_amdgcn_mfma_f32_32x32x16_bf16(a0, b0, acc[0][0], 0, 0, 0);
                acc[0][1] = __builtin_amdgcn_mfma_f32_32x32x16_bf16(a0, b1, acc[0][1], 0, 0, 0);
                acc[1][0] = __builtin_amdgcn_mfma_f32_32x32x16_bf16(a1, b0, acc[1][0], 0, 0, 0);
                acc[1][1] = __builtin_amdgcn_mfma_f32_32x32x16_bf16(a1, b1, acc[1][1], 0, 0, 0);
            }
            __syncthreads();
        }
#pragma unroll
        for (int i = 0; i < 2; ++i)
#pragma unroll
            for (int j = 0; j < 2; ++j) {
                int col = wn + j * 32 + row32;
                if (col < ncols) {
                    float bj = bp[col];
#pragma unroll
                    for (int r = 0; r < 16; ++r) {
                        int row = wm + i * 32 + (r & 3) + 8 * (r >> 2) + 4 * half;
                        dst[row * ncols + col] = acc[i][j][r] + bj;
                    }
                }
            }
    };

    run_gemm(hbuf,        W51p, b51p, x51s, 20);
    run_gemm(hbuf + 1024, W52p, b52p, x52s, 11);
    __syncthreads();

    if (tid < 128) {
        int b = bm + tid;

        float w[10], m = -1e30f;
#pragma unroll
        for (int h = 0; h < 10; ++h) { w[h] = wt[h]; m = fmaxf(m, w[h]); }
        float ssum = 0.f;
#pragma unroll
        for (int h = 0; h < 10; ++h) { w[h] = __expf(w[h] - m); ssum += w[h]; }
        float winv = 1.f / ssum;

        float4 xv = ((const float4*)x)[b];
        float th1 = xv.x * std_[0] + mean[0];
        float w1v = xv.y * std_[1] + mean[1];
        float th2 = xv.z * std_[2] + mean[2];
        float w2v = xv.w * std_[3] + mean[3];
        float s1 = sinf(th1), c1 = cosf(th1);
        float s2 = sinf(th2), c2 = cosf(th2);
        float px = 3.f * c1 + 3.f * c2 - 0.f;
        float py = 3.f * s1 + 3.f * s2 - 7.f;
        float vx = -3.f * s1 * w1v - 3.f * s2 * w2v;
        float vy =  3.f * c1 * w1v + 3.f * c2 * w2v;
        float barrier = px * px + py * py - 16.f;
        float b_dot = 2.f * (px * vx + py * vy);
        float Lf2b = 2.f * vx * vx + 2.f * vy * vy
                   + 2.f * px * (-3.f * c1 * w1v * w1v - 3.f * c2 * w2v * w2v)
                   + 2.f * py * (-3.f * s1 * w1v * w1v - 3.f * s2 * w2v * w2v);
        float g1 = 2.f * px * (-3.f * s1) + 2.f * py * (3.f * c1);
        float g2 = 2.f * px * (-3.f * s2) + 2.f * py * (3.f * c2);
        float Gx = -g1, Gy = -g2;
        float Gdot = Gx * Gx + Gy * Gy;

        float alpha = 4.f / (1.f + expf(-x52s[tid * 11 + 0]));

        float rx = 0.f, ry = 0.f;
#pragma unroll
        for (int h = 0; h < 10; ++h) {
            float r0 = x51s[tid * 20 + 2 * h];
            float r1 = x51s[tid * 20 + 2 * h + 1];
            float beta = 4.f / (1.f + expf(-x52s[tid * 11 + 1 + h]));
            float hh = Lf2b + (alpha + beta) * b_dot + alpha * beta * barrier;
            float ux = -r0, uy = -r1;
            float viol = ux * Gx + uy * Gy - hh;
            float lam = fmaxf(viol / Gdot, 0.f);
            float sx = ux - lam * Gx;
            float sy = uy - lam * Gy;
            float wk = w[h] * winv;
            rx += wk * sx; ry += wk * sy;
        }
        out[2 * b]     = (rx - mean_label[0]) / std_label[0];
        out[2 * b + 1] = (ry - mean_label[1]) / std_label[1];
    }
}

extern "C" void kernel_launch(void* const* d_in, const int* in_sizes, int n_in,
                              void* d_out, int out_size, void* d_ws, size_t ws_size,
                              hipStream_t stream) {
    const float* x    = (const float*)d_in[0];
    const float* mean = (const float*)d_in[2];
    const float* std_ = (const float*)d_in[3];
    const float* mean_label = (const float*)d_in[4];
    const float* std_label  = (const float*)d_in[5];
    const float* W1  = (const float*)d_in[6];
    const float* b1  = (const float*)d_in[7];
    const float* W2  = (const float*)d_in[8];
    const float* b2  = (const float*)d_in[9];
    const float* W31 = (const float*)d_in[10];
    const float* b31 = (const float*)d_in[11];
    const float* W32 = (const float*)d_in[12];
    const float* b32 = (const float*)d_in[13];
    const float* W41 = (const float*)d_in[14];
    const float* b41 = (const float*)d_in[15];
    const float* W42 = (const float*)d_in[16];
    const float* b42 = (const float*)d_in[17];
    const float* W51 = (const float*)d_in[18];
    const float* b51 = (const float*)d_in[19];
    const float* W52 = (const float*)d_in[20];
    const float* b52 = (const float*)d_in[21];
    const float* wt  = (const float*)d_in[22];

    const int B = in_sizes[0] / 4;       // 16384

    char* wsp = (char*)d_ws;
    size_t off = 0;
    auto alloc = [&](size_t bytes) {
        void* p = wsp + off;
        off += (bytes + 255) & ~(size_t)255;
        return p;
    };
    u8*    W2q  = (u8*)   alloc((size_t)2048 * 2048);
    float* sW2  = (float*)alloc(2048 * 4);
    float* Wsum2= (float*)alloc(2048 * 4);
    u8*    h1q  = (u8*)   alloc((size_t)B * 2048);
    float* sA1  = (float*)alloc((size_t)B * 4);
    float* muA1 = (float*)alloc((size_t)B * 4);
    u16*   W31b = (u16*)  alloc((size_t)1024 * 2048 * 2);  // W31b||W32b contiguous
    u16*   W32b = (u16*)  alloc((size_t)1024 * 2048 * 2);
    u16*   W41b = (u16*)  alloc((size_t)1024 * 1024 * 2);
    u16*   W42b = (u16*)  alloc((size_t)1024 * 1024 * 2);
    u16*   W51p = (u16*)  alloc((size_t)128 * 1024 * 2);
    u16*   W52p = (u16*)  alloc((size_t)128 * 1024 * 2);
    float* b51p = (float*)alloc(512);
    float* b52p = (float*)alloc(512);
    float* b3c  = (float*)alloc(2048 * 4);
    u16*   bufA = (u16*)  alloc((size_t)B * 2048 * 2);   // h31||h32
    u16*   bufB = (u16*)  alloc((size_t)B * 2048 * 2);   // h2 -> h41||h42
    const u16* NUL = nullptr;

    // stage-1 prep: W2 row-quant + layer-1-with-quant (gates L2)
    k_prep1<<<1536, 256, 0, stream>>>(W2, W2q, sW2, Wsum2,
                                      x, W1, b1, h1q, sA1, muA1);

    // L2 (i8): h2 = relu(deq(h1q @ W2q^T) + b2)  [B,2048] -> bufB (bf16)
    // grid: 16 x (64 GEMM y-groups + 401 backfill rows = 6416 prep blocks)
    k_gemmq<<<dim3(16, 64 + 401), 256, 0, stream>>>(
        h1q, W2q, sA1, muA1, sW2, Wsum2, b2, bufB, 2048, 2048, 1, 64,
        W31, W31b, W32, W32b, W41, W41b, W42, W42b,
        W51, W51p, b51, b51p, W52, W52p, b52, b52p, b31, b32, b3c);
    // L3 fused (bf16): h31||h32 = relu(h2 @ [W31;W32]^T + b3c) -> bufA
    k_gemm256<<<dim3(16, 64), 256, 0, stream>>>(
        bufB, W31b, b3c, bufA, 2048, 2048, 2048, 1, 64,
        NUL, NUL, nullptr, nullptr, 0);
    // L4 fused (bf16): h41 -> bufB[:, :1024], h42 -> bufB[:, 1024:]
    k_gemm256<<<dim3(8, 128), 256, 0, stream>>>(
        bufA, W41b, b41, bufB, 1024, 2048, 2048, 1, 128,
        bufA + 1024, W42b, b42, bufB + 1024, 64);
    // fused heads GEMMs + physics/QP/softmax epilogue
    k_heads_final<<<B / 128, 256, 0, stream>>>(
        bufB, W51p, b51p, W52p, b52p, x, mean, std_,
        mean_label, std_label, wt, (float*)d_out);
}